// Round 6
// baseline (277.013 us; speedup 1.0000x reference)
//
#include <hip/hip_runtime.h>
#include <hip/hip_bf16.h>
#include <math.h>

#define T_DIM 256
#define B_DIM 256
#define H_DIM 512
#define K_DIM 64
#define LN2F 0.69314718055994531f

typedef __attribute__((ext_vector_type(8))) short bfrag_t;  // 8 bf16 (4 VGPRs)
typedef __attribute__((ext_vector_type(4))) float f4_t;     // 4 fp32

// Pack 8 fp32 -> 8 bf16 (RNE) for an MFMA A/B fragment.
__device__ inline bfrag_t pack8(float4 a, float4 b) {
  union { bfrag_t v; __hip_bfloat162 h[4]; } u;
  u.h[0] = __float22bfloat162_rn(float2{a.x, a.y});
  u.h[1] = __float22bfloat162_rn(float2{a.z, a.w});
  u.h[2] = __float22bfloat162_rn(float2{b.x, b.y});
  u.h[3] = __float22bfloat162_rn(float2{b.z, b.w});
  return u.v;
}

// ---------------------------------------------------------------------------
// Emission GEMM v6: em = exp(hid·W^T + bias) in the DP's permuted layout.
// Same as r5 (M=64 x N=64 tile, bf16 LDS staging, LDS epilogue) except the
// final stores are now WAVE-CONTIGUOUS: per store instruction a wave covers
// 64 consecutive 16B granules (1 KB contiguous), eliminating the 16B@64B
// strided pattern suspected of write amplification.
// ---------------------------------------------------------------------------
__global__ __launch_bounds__(256, 3) void emis_gemm6(
    const float* __restrict__ hid,   // [T*B, H]
    const float* __restrict__ W,     // [K,H]
    const float* __restrict__ bias,  // [K]
    float* __restrict__ emP)
{
  __shared__ __hip_bfloat16 AsH[2][64 * 72];     // 2 x 9216 B
  float* Cs = (float*)&AsH[0][0];                // epilogue reuse (17388 B <= 18432)

  const int tid  = threadIdx.x;
  const int wv   = tid >> 6;
  const int lane = tid & 63;
  const int l16  = lane & 15;
  const int quad = lane >> 4;
  const int m0   = blockIdx.x * 64;   // 64 consecutive m: t fixed, b in [b0,b0+64)

  // B-frags: W row j = wv*16 + l16, 16 k-chunks of 32. B[k=quad*8+r][n=l16].
  bfrag_t bw[16];
  {
    const float* wr = W + (size_t)(wv * 16 + l16) * H_DIM + quad * 8;
#pragma unroll
    for (int kc = 0; kc < 16; ++kc)
      bw[kc] = pack8(*(const float4*)(wr + kc * 32), *(const float4*)(wr + kc * 32 + 4));
  }

  // Staging: thread -> row sr = tid>>2 (64 rows), k-segment sc = (tid&3)*16.
  const int sr = tid >> 2;
  const int sc = (tid & 3) << 4;
  const float* hrow = hid + (size_t)(m0 + sr) * H_DIM + sc;

  f4_t acc[4];
#pragma unroll
  for (int mt = 0; mt < 4; ++mt) acc[mt] = (f4_t){0.f, 0.f, 0.f, 0.f};

  float4 p0 = *(const float4*)(hrow + 0);
  float4 p1 = *(const float4*)(hrow + 4);
  float4 p2 = *(const float4*)(hrow + 8);
  float4 p3 = *(const float4*)(hrow + 12);
  *(bfrag_t*)(&AsH[0][sr * 72 + sc + 0]) = pack8(p0, p1);
  *(bfrag_t*)(&AsH[0][sr * 72 + sc + 8]) = pack8(p2, p3);
  __syncthreads();

#pragma unroll
  for (int it = 0; it < 8; ++it) {
    if (it < 7) {
      p0 = *(const float4*)(hrow + (it + 1) * 64 + 0);
      p1 = *(const float4*)(hrow + (it + 1) * 64 + 4);
      p2 = *(const float4*)(hrow + (it + 1) * 64 + 8);
      p3 = *(const float4*)(hrow + (it + 1) * 64 + 12);
    }
#pragma unroll
    for (int kc2 = 0; kc2 < 2; ++kc2) {
#pragma unroll
      for (int mt = 0; mt < 4; ++mt) {
        const bfrag_t af =
            *(const bfrag_t*)(&AsH[it & 1][(mt * 16 + l16) * 72 + kc2 * 32 + quad * 8]);
        acc[mt] = __builtin_amdgcn_mfma_f32_16x16x32_bf16(af, bw[it * 2 + kc2], acc[mt], 0, 0, 0);
      }
    }
    if (it < 7) {
      *(bfrag_t*)(&AsH[(it + 1) & 1][sr * 72 + sc + 0]) = pack8(p0, p1);
      *(bfrag_t*)(&AsH[(it + 1) & 1][sr * 72 + sc + 8]) = pack8(p2, p3);
    }
    __syncthreads();
  }

  // ---- epilogue: exp(acc + bias) -> LDS [m][j] (stride 68)
  const float bn = bias[wv * 16 + l16];
#pragma unroll
  for (int mt = 0; mt < 4; ++mt)
#pragma unroll
    for (int r = 0; r < 4; ++r)
      Cs[(mt * 16 + quad * 4 + r) * 68 + wv * 16 + l16] = __expf(acc[mt][r] + bn);
  __syncthreads();

  // ---- wave-contiguous stores: granule G = c*64 + ln of row (g0+gl, t).
  // value(G) with G = (c*16 + b2)*4 + i2  lives at Cs[(gl*16+b2)*68 + i2*16 + c*4]
  const int t  = m0 >> 8;
  const int g0 = (m0 & 255) >> 4;
  const int gl = tid >> 6;
  const int ln = tid & 63;
  const int i2 = ln & 3;
  const int b2 = (ln >> 2) & 15;
  float* rowout = emP + (((size_t)(g0 + gl) * 256 + t) * 64) * 16;
#pragma unroll
  for (int c = 0; c < 4; ++c) {
    const float4 v = *(const float4*)(&Cs[(gl * 16 + b2) * 68 + i2 * 16 + c * 4]);
    *(float4*)(rowout + (size_t)(c * 64 + ln) * 4) = v;
  }
}

// ---------------------------------------------------------------------------
// CRF DP, forward/backward meet-in-the-middle (r4 structure, verified at
// absmax 0.0). 4-deep explicit register prefetch ring — r5's 8-deep ring is
// suspected to have spilled (~240 VGPRs); this stays ~170.
// wave0 change vs r4: eend[] no longer held during the loop (recomputed at
// the end), freeing 16 VGPRs.
// ---------------------------------------------------------------------------
__global__ __launch_bounds__(128) void crf_dp6(
    const float* __restrict__ emP,
    const int* __restrict__ lens,
    const int* __restrict__ tags,
    const float* __restrict__ trans,
    const float* __restrict__ beginT,
    const float* __restrict__ endT,
    float* __restrict__ out)
{
  const int g    = blockIdx.x;
  const int tid  = threadIdx.x;
  const int wv   = tid >> 6;     // 0 = forward, 1 = backward
  const int lane = tid & 63;
  const int n    = lane & 15;
  const int q    = lane >> 4;
  const int b    = g * 16 + n;

  __shared__ float xs[64 * 16];  // x_127 per fwd-lane
  __shared__ int   Lxs[64];
  __shared__ float s0d[16];      // snap·eend per column
  __shared__ int   Ls0[16];
  __shared__ float gpart;        // wave0 gold partial

  const int len = lens[b];
  const int cap = len - 1;
  const float* base = emP + (((size_t)g * 256) * 64 + lane) * 16;

  float y[16];
  int Lint = 0;
  bfrag_t bf0, bf1;
  float wA[16], wB[16], wC[16], wD[16];
  float g0 = 0.f;   // per-lane gold partial (this wave's t-range)

#define LOADW(dst, t) { \
    const float4 _a = *(const float4*)(base + (size_t)(t) * 1024 + 0); \
    const float4 _b = *(const float4*)(base + (size_t)(t) * 1024 + 4); \
    const float4 _c = *(const float4*)(base + (size_t)(t) * 1024 + 8); \
    const float4 _d = *(const float4*)(base + (size_t)(t) * 1024 + 12); \
    dst[0]=_a.x; dst[1]=_a.y; dst[2]=_a.z; dst[3]=_a.w; \
    dst[4]=_b.x; dst[5]=_b.y; dst[6]=_b.z; dst[7]=_b.w; \
    dst[8]=_c.x; dst[9]=_c.y; dst[10]=_c.z; dst[11]=_c.w; \
    dst[12]=_d.x; dst[13]=_d.y; dst[14]=_d.z; dst[15]=_d.w; }

#define RESCALE() { \
    float _mx = y[0]; \
    _Pragma("unroll") for (int k = 1; k < 16; ++k) _mx = fmaxf(_mx, y[k]); \
    _mx = fmaxf(_mx, __shfl_xor(_mx, 16)); \
    _mx = fmaxf(_mx, __shfl_xor(_mx, 32)); \
    int _e; (void)frexpf(_mx, &_e); \
    Lint += _e; \
    _Pragma("unroll") for (int k = 0; k < 16; ++k) y[k] = ldexpf(y[k], -_e); }

#define BUILDBV(S) { \
    union { bfrag_t v; __hip_bfloat162 h[4]; } _u0, _u1; \
    _u0.h[0] = __float22bfloat162_rn(float2{S[0], S[1]}); \
    _u0.h[1] = __float22bfloat162_rn(float2{S[2], S[3]}); \
    _u0.h[2] = __float22bfloat162_rn(float2{S[4], S[5]}); \
    _u0.h[3] = __float22bfloat162_rn(float2{S[6], S[7]}); \
    _u1.h[0] = __float22bfloat162_rn(float2{S[8], S[9]}); \
    _u1.h[1] = __float22bfloat162_rn(float2{S[10], S[11]}); \
    _u1.h[2] = __float22bfloat162_rn(float2{S[12], S[13]}); \
    _u1.h[3] = __float22bfloat162_rn(float2{S[14], S[15]}); \
    bf0 = _u0.v; bf1 = _u1.v; }

  const f4_t zro = (f4_t){0.f, 0.f, 0.f, 0.f};

#define EMPIDX(tt, tg) (((((size_t)g * 256 + (tt)) * 64 + (((tg) >> 2) & 3) * 16 + n) << 4) \
                        + ((tg) >> 4) * 4 + ((tg) & 3))

  if (wv == 0) {
    // ---- forward wave ----
    bfrag_t aE[8];
#pragma unroll
    for (int jt = 0; jt < 4; ++jt)
#pragma unroll
      for (int kt = 0; kt < 2; ++kt) {
        union { bfrag_t v; __hip_bfloat16 h[8]; } u;
#pragma unroll
        for (int r = 0; r < 8; ++r) {
          const int i = (2 * kt + (r >> 2)) * 16 + q * 4 + (r & 3);
          u.h[r] = __float2bfloat16(__expf(trans[(jt * 16 + n) * K_DIM + i]));
        }
        aE[jt * 2 + kt] = u.v;
      }

    float snap[16];
    int Lsnap = 0;
    LOADW(wA, 0);
#pragma unroll
    for (int k = 0; k < 16; ++k) {
      const int j = (k >> 2) * 16 + q * 4 + (k & 3);
      y[k] = wA[k] * __expf(beginT[j]);
      snap[k] = (cap == 0) ? y[k] : 0.0f;
    }
    RESCALE(); BUILDBV(y);
    LOADW(wA, 1); LOADW(wB, 2); LOADW(wC, 3); LOADW(wD, 4);

#define STEPF(T, W, RSC) { \
    f4_t _a0 = __builtin_amdgcn_mfma_f32_16x16x32_bf16(aE[0], bf0, zro, 0, 0, 0); \
    f4_t _a1 = __builtin_amdgcn_mfma_f32_16x16x32_bf16(aE[2], bf0, zro, 0, 0, 0); \
    f4_t _a2 = __builtin_amdgcn_mfma_f32_16x16x32_bf16(aE[4], bf0, zro, 0, 0, 0); \
    f4_t _a3 = __builtin_amdgcn_mfma_f32_16x16x32_bf16(aE[6], bf0, zro, 0, 0, 0); \
    _a0 = __builtin_amdgcn_mfma_f32_16x16x32_bf16(aE[1], bf1, _a0, 0, 0, 0); \
    _a1 = __builtin_amdgcn_mfma_f32_16x16x32_bf16(aE[3], bf1, _a1, 0, 0, 0); \
    _a2 = __builtin_amdgcn_mfma_f32_16x16x32_bf16(aE[5], bf1, _a2, 0, 0, 0); \
    _a3 = __builtin_amdgcn_mfma_f32_16x16x32_bf16(aE[7], bf1, _a3, 0, 0, 0); \
    _Pragma("unroll") for (int r = 0; r < 4; ++r) { \
      y[r]      = _a0[r] * W[r]; \
      y[4 + r]  = _a1[r] * W[4 + r]; \
      y[8 + r]  = _a2[r] * W[8 + r]; \
      y[12 + r] = _a3[r] * W[12 + r]; } \
    const bool _hit = ((T) == cap); \
    _Pragma("unroll") for (int k = 0; k < 16; ++k) snap[k] = _hit ? y[k] : snap[k]; \
    Lsnap = _hit ? Lint : Lsnap; \
    if (RSC) { RESCALE(); } \
    BUILDBV(y); }

    int t = 1;
    for (int it = 0; it < 31; ++it, t += 4) {
      STEPF(t, wA, 0);     LOADW(wA, t + 4);
      STEPF(t + 1, wB, 0); LOADW(wB, t + 5);
      STEPF(t + 2, wC, 0); LOADW(wC, t + 6);
      STEPF(t + 3, wD, 1); LOADW(wD, t + 7);
    }
    STEPF(125, wA, 0); STEPF(126, wB, 0); STEPF(127, wC, 0);

    // publish x_127 / scales / snap-dot
#pragma unroll
    for (int k = 0; k < 16; ++k) xs[lane * 16 + k] = y[k];
    Lxs[lane] = Lint;
    float sd = 0.f;
#pragma unroll
    for (int k = 0; k < 16; ++k)
      sd += snap[k] * __expf(endT[(k >> 2) * 16 + q * 4 + (k & 3)]);
    sd += __shfl_xor(sd, 16);
    sd += __shfl_xor(sd, 32);
    if (lane < 16) { s0d[lane] = sd; Ls0[lane] = Lsnap; }

    // gold partial: t in [0,128)
    for (int c = 0; c < 32; ++c) {
      const int tt = q + 4 * c;
      if (tt < len) {
        const int tg = tags[(size_t)tt * B_DIM + b];
        float v = __logf(emP[EMPIDX(tt, tg)]);
        v += (tt == 0) ? beginT[tg]
                       : trans[(size_t)tg * K_DIM + tags[(size_t)(tt - 1) * B_DIM + b]];
        if (tt == cap) v += endT[tg];
        g0 += v;
      }
    }
    float gr = g0;
#pragma unroll
    for (int o = 1; o < 64; o <<= 1) gr += __shfl_xor(gr, o);
    if (lane == 0) gpart = gr;
  } else {
    // ---- backward wave ----
    float eend[16];
#pragma unroll
    for (int k = 0; k < 16; ++k)
      eend[k] = __expf(endT[(k >> 2) * 16 + q * 4 + (k & 3)]);

    bfrag_t aET[8];
#pragma unroll
    for (int jt = 0; jt < 4; ++jt)
#pragma unroll
      for (int kt = 0; kt < 2; ++kt) {
        union { bfrag_t v; __hip_bfloat16 h[8]; } u;
#pragma unroll
        for (int r = 0; r < 8; ++r) {
          const int i = (2 * kt + (r >> 2)) * 16 + q * 4 + (r & 3);
          u.h[r] = __float2bfloat16(__expf(trans[(size_t)i * K_DIM + (jt * 16 + n)]));
        }
        aET[jt * 2 + kt] = u.v;
      }

#pragma unroll
    for (int k = 0; k < 16; ++k) y[k] = 0.f;
    LOADW(wA, 255); LOADW(wB, 254); LOADW(wC, 253); LOADW(wD, 252);

#define STEPB(T, W, RSC) { \
    const bool _hit = ((T) == cap); \
    float _d[16]; \
    _Pragma("unroll") for (int k = 0; k < 16; ++k) \
      _d[k] = (_hit ? eend[k] : y[k]) * W[k]; \
    BUILDBV(_d); \
    f4_t _a0 = __builtin_amdgcn_mfma_f32_16x16x32_bf16(aET[0], bf0, zro, 0, 0, 0); \
    f4_t _a1 = __builtin_amdgcn_mfma_f32_16x16x32_bf16(aET[2], bf0, zro, 0, 0, 0); \
    f4_t _a2 = __builtin_amdgcn_mfma_f32_16x16x32_bf16(aET[4], bf0, zro, 0, 0, 0); \
    f4_t _a3 = __builtin_amdgcn_mfma_f32_16x16x32_bf16(aET[6], bf0, zro, 0, 0, 0); \
    _a0 = __builtin_amdgcn_mfma_f32_16x16x32_bf16(aET[1], bf1, _a0, 0, 0, 0); \
    _a1 = __builtin_amdgcn_mfma_f32_16x16x32_bf16(aET[3], bf1, _a1, 0, 0, 0); \
    _a2 = __builtin_amdgcn_mfma_f32_16x16x32_bf16(aET[5], bf1, _a2, 0, 0, 0); \
    _a3 = __builtin_amdgcn_mfma_f32_16x16x32_bf16(aET[7], bf1, _a3, 0, 0, 0); \
    _Pragma("unroll") for (int r = 0; r < 4; ++r) { \
      y[r]      = _a0[r]; \
      y[4 + r]  = _a1[r]; \
      y[8 + r]  = _a2[r]; \
      y[12 + r] = _a3[r]; } \
    if (RSC) { RESCALE(); } }

    int t = 255;
    for (int it = 0; it < 32; ++it, t -= 4) {
      STEPB(t, wA, 0);     LOADW(wA, t - 4);
      STEPB(t - 1, wB, 0); LOADW(wB, t - 5);
      STEPB(t - 2, wC, 0); LOADW(wC, t - 6);
      STEPB(t - 3, wD, 1); LOADW(wD, t - 7);
    }
    // y = u_127 (scale Lint = Lu)

    // gold partial: t in [128,256)
    for (int c = 0; c < 32; ++c) {
      const int tt = 128 + q + 4 * c;
      if (tt < len) {
        const int tg = tags[(size_t)tt * B_DIM + b];
        float v = __logf(emP[EMPIDX(tt, tg)]);
        v += trans[(size_t)tg * K_DIM + tags[(size_t)(tt - 1) * B_DIM + b]];
        if (tt == cap) v += endT[tg];
        g0 += v;
      }
    }
  }

  __syncthreads();

  if (wv == 1) {
    float dot1 = 0.f;
#pragma unroll
    for (int k = 0; k < 16; ++k) dot1 += xs[lane * 16 + k] * y[k];
    dot1 += __shfl_xor(dot1, 16);
    dot1 += __shfl_xor(dot1, 32);

    const bool hi = (cap >= 128);
    const float dsel = hi ? dot1 : s0d[n];
    const float Lsel = (float)(hi ? (Lxs[lane] + Lint) : Ls0[n]);
    const float f = __logf(dsel) + Lsel * LN2F;

    float r = 0.25f * f - g0;
#pragma unroll
    for (int o = 1; o < 64; o <<= 1) r += __shfl_xor(r, o);
    if (lane == 0) atomicAdd(out, r - gpart);
  }
}

// ---------------------------------------------------------------------------
extern "C" void kernel_launch(void* const* d_in, const int* in_sizes, int n_in,
                              void* d_out, int out_size, void* d_ws, size_t ws_size,
                              hipStream_t stream) {
  const float* hiddens = (const float*)d_in[0];  // [T,B,H]
  const int*   lens    = (const int*)  d_in[1];  // [B]
  const int*   tags    = (const int*)  d_in[2];  // [T,B]
  const float* W       = (const float*)d_in[3];  // [K,H]
  const float* bias    = (const float*)d_in[4];  // [K]
  const float* beginT  = (const float*)d_in[5];  // [K]
  const float* trans   = (const float*)d_in[6];  // [K,K]
  const float* endT    = (const float*)d_in[7];  // [K]

  float* emP = (float*)d_ws;   // 16*256*64*16 fp32 = 16.8 MB
  float* out = (float*)d_out;

  hipMemsetAsync(out, 0, sizeof(float), stream);
  emis_gemm6<<<(T_DIM * B_DIM) / 64, 256, 0, stream>>>(hiddens, W, bias, emP);
  crf_dp6<<<16, 128, 0, stream>>>(emP, lens, tags, trans, beginT, endT, out);
}